// Round 12
// baseline (138.572 us; speedup 1.0000x reference)
//
#include <hip/hip_runtime.h>
#include <math.h>

typedef _Float16 f16;
typedef _Float16 half4_t __attribute__((ext_vector_type(4)));
typedef _Float16 half8_t __attribute__((ext_vector_type(8)));
typedef float floatx4 __attribute__((ext_vector_type(4)));

// ------------------------------------------------------------------
// Kernel P: repack weights fp32 -> f16, transposed [col][k] so B-operand
// fragments (k-chunks of 8) are contiguous 16B loads.
// ------------------------------------------------------------------
__global__ __launch_bounds__(256) void prep_weights(
    const float* __restrict__ W1, const float* __restrict__ W2,
    const float* __restrict__ W3, f16* __restrict__ wt) {
  int t = blockIdx.x * 256 + threadIdx.x;
  if (t < 8192) {                       // W1t [128][64]
    int c = t >> 6, k = t & 63;
    wt[t] = (f16)W1[k * 128 + c];
  } else if (t < 24576) {               // W2t [128][128]
    int u = t - 8192;
    int c = u >> 7, k = u & 127;
    wt[t] = (f16)W2[k * 128 + c];
  } else if (t < 43008) {               // W3t [144][128], cols 136..143 zero
    int u = t - 24576;
    int c = u >> 7, k = u & 127;
    wt[t] = (f16)((c < 136) ? W3[k * 136 + c] : 0.0f);
  }
}

// fast tanh: tanh(x) = 1 - 2/(e^{2x}+1)
__device__ __forceinline__ float fast_tanh(float v) {
  float e = __builtin_amdgcn_exp2f(v * 2.885390081777926814f);  // 2*log2(e)
  return 1.0f - 2.0f * __builtin_amdgcn_rcpf(e + 1.0f);
}

// ---- DPP wave64 sum: row_shr 1/2/4/8 then row_bcast 15/31; total in lane 63.
template <int CTRL>
__device__ __forceinline__ float dpp_add(float v) {
  int t = __builtin_amdgcn_update_dpp(0, __builtin_bit_cast(int, v), CTRL,
                                      0xf, 0xf, true);
  return v + __builtin_bit_cast(float, t);
}
__device__ __forceinline__ float wsum(float v) {
  v = dpp_add<0x111>(v);  // row_shr:1
  v = dpp_add<0x112>(v);  // row_shr:2
  v = dpp_add<0x114>(v);  // row_shr:4
  v = dpp_add<0x118>(v);  // row_shr:8
  v = dpp_add<0x142>(v);  // row_bcast:15
  v = dpp_add<0x143>(v);  // row_bcast:31
  return __builtin_bit_cast(
      float, __builtin_amdgcn_readlane(__builtin_bit_cast(int, v), 63));
}

// round floatx4 -> half4 via packed RTZ converts
__device__ __forceinline__ half4_t to_h(floatx4 v) {
  auto p0 = __builtin_amdgcn_cvt_pkrtz(v[0], v[1]);
  auto p1 = __builtin_amdgcn_cvt_pkrtz(v[2], v[3]);
  half4_t h;
  h[0] = p0[0]; h[1] = p0[1]; h[2] = p1[0]; h[3] = p1[1];
  return h;
}

__device__ __forceinline__ float dot4(floatx4 a, floatx4 b) {
  return a[0] * b[0] + a[1] * b[1] + a[2] * b[2] + a[3] * b[3];
}

// ------------------------------------------------------------------
// p = expm(B - m I), m = trace/16. Canonical symmetric fragment layout:
// lane value_i = X[l&15][4*(l>>4)+i] is simultaneously a valid A, B and C/D
// layout for v_mfma_f32_16x16x16_f16 (polynomials of a symmetric matrix stay
// symmetric -> zero cross-lane data movement). Degree-4 Paterson-Stockmeyer,
// spectral bound theta <= 0.354 via Frobenius power-of-2 scaling.
// (R11's deg-8 reverted: this data's norms give s<=1 already, so deg-8's
// extra ~45 VALU/call bought nothing -- measured +3.5 us, VALU 20.6->26 us.)
// ------------------------------------------------------------------
__device__ __forceinline__ floatx4 expm_c(floatx4 b, floatx4 I4, float& m) {
  float s2 = wsum(dot4(b, b));
  float td = wsum(dot4(I4, b));
  m = td * 0.0625f;
  float fr2 = fmaxf(s2 - td * m, 1e-30f);  // ||B - mI||_F^2
  int e2 = (int)(__builtin_bit_cast(unsigned, fr2) >> 23) - 127;
  int s = (e2 + 5) >> 1;  // guarantees 2^-s * fr <= 2^-1.5 = 0.354
  s = s < 0 ? 0 : (s > 12 ? 12 : s);
  s = __builtin_amdgcn_readfirstlane(s);
  float sc = __builtin_bit_cast(float, (unsigned)(127 - s) << 23);  // 2^-s
  b = (b - I4 * m) * sc;
  half4_t bh = to_h(b);
  floatx4 zero = {0.f, 0.f, 0.f, 0.f};
  floatx4 a2 = __builtin_amdgcn_mfma_f32_16x16x16f16(bh, bh, zero, 0, 0, 0);
  // deg-4 Taylor: I + b + a2*(I/2 + b/6 + a2/24)
  floatx4 t = I4 * 0.5f + b * (1.f / 6.f) + a2 * (1.f / 24.f);
  floatx4 p = __builtin_amdgcn_mfma_f32_16x16x16f16(to_h(a2), to_h(t), I4 + b,
                                                    0, 0, 0);
  for (int k = 0; k < s; ++k) {
    half4_t ph = to_h(p);
    p = __builtin_amdgcn_mfma_f32_16x16x16f16(ph, ph, zero, 0, 0, 0);
  }
  return p;
}

// ------------------------------------------------------------------
// Fused kernel: R8 structure (harness-verified 50.3 us: stream W1,
// W2/W3 resident, __launch_bounds__(256,3), 2048x256, ldata in LDS).
// R12 change: the layer-3 output is stored in LDS as the EXPANDED
// symmetric 16x16 matrix per batch row ([32][16][16] f16, 16 KB) instead
// of tril-packed [32][144]. L3 decodes tril index -> (hi,lo) once per
// thread and writes (hi,lo)+(lo,hi); the expm b-load becomes ONE aligned
// ds_read_b64 per lane (bank-optimal) + diag 4x/offdiag 2x scale --
// replacing 4 scattered ds_read_u16 + ~25 VALU of tril index math per
// matrix (R8 counters: 819200 LDS bank conflicts). Bit-identical values.
// ------------------------------------------------------------------
__global__ __launch_bounds__(256, 3) void fused_kernel(
    const float* __restrict__ x, const float* __restrict__ b1,
    const float* __restrict__ b2v, const float* __restrict__ b3,
    const f16* __restrict__ wt, float* __restrict__ out) {
  __shared__ f16 act1[2048];                      // 16 rows x 128 cols (h1)
  __shared__ f16 act2[2048];                      // 16 rows x 128 cols (h2)
  __shared__ __align__(16) f16 mats[32 * 256];    // 32 x [16][16] symmetric

  const int lane = threadIdx.x & 63;
  const int w = threadIdx.x >> 6;  // wave 0..3
  const int cl = lane & 15;        // A-row / C-col index
  const int q = lane >> 4;         // quad: k-chunk / C-row-group
  const f16* w1t = wt;             // [128][64]
  const f16* w2t = wt + 8192;      // [128][128]
  const f16* w3t = wt + 24576;     // [144][128]

  // ---- one-time: this wave's quarter of W2/W3 fragments + biases ----
  half8_t w2f[2][4], w3f[3][4];
  float bias1[2], bias2[2], bias3[3];
#pragma unroll
  for (int j = 0; j < 2; ++j) {
    int c8g = w + 4 * j;
    int c = c8g * 16 + cl;
#pragma unroll
    for (int ks = 0; ks < 4; ++ks)
      w2f[j][ks] = *(const half8_t*)(w2t + c * 128 + ks * 32 + q * 8);
    bias1[j] = b1[c];
    bias2[j] = b2v[c];
  }
#pragma unroll
  for (int j = 0; j < 3; ++j) {
    int c8g = w + 4 * j;
    int c8c = c8g < 9 ? c8g : 8;  // clamp so loads stay in-bounds (unused)
    int c = c8c * 16 + cl;
#pragma unroll
    for (int ks = 0; ks < 4; ++ks)
      w3f[j][ks] = *(const half8_t*)(w3t + c * 128 + ks * 32 + q * 8);
    int cc = c8g * 16 + cl;
    bias3[j] = (cc < 136) ? b3[cc] : 0.f;
  }

  // ---- tril index -> (hi,lo) decode, once per thread per j-group ----
  int hi_[3], lo_[3];
#pragma unroll
  for (int j = 0; j < 3; ++j) {
    int c = (w + 4 * j) * 16 + cl;
    int cc = c < 136 ? c : 0;  // garbage-guard (unused when c>=136)
    int hi = (int)((sqrtf(8.f * (float)cc + 1.f) - 1.f) * 0.5f);
    if ((hi + 1) * (hi + 2) / 2 <= cc) ++hi;  // float-rounding fixups
    if (hi * (hi + 1) / 2 > cc) --hi;
    hi_[j] = hi;
    lo_[j] = cc - hi * (hi + 1) / 2;
  }

  const int r0b = blockIdx.x * 32;
  // prefetch row-tile 0's x rows (all 4 waves load same addrs: L1-hit)
  const float* xp = x + (size_t)(r0b + cl) * 64 + q * 8;
  floatx4 v0 = *(const floatx4*)xp;
  floatx4 v1 = *(const floatx4*)(xp + 4);
  floatx4 v2 = *(const floatx4*)(xp + 32);
  floatx4 v3 = *(const floatx4*)(xp + 36);

  for (int t = 0; t < 2; ++t) {
    half8_t a0, a1;
#pragma unroll
    for (int i = 0; i < 4; ++i) {
      a0[i] = (f16)v0[i]; a0[i + 4] = (f16)v1[i];
      a1[i] = (f16)v2[i]; a1[i + 4] = (f16)v3[i];
    }
    if (t == 0) {  // prefetch tile 1's x rows
      xp = x + (size_t)(r0b + 16 + cl) * 64 + q * 8;
      v0 = *(const floatx4*)xp;
      v1 = *(const floatx4*)(xp + 4);
      v2 = *(const floatx4*)(xp + 32);
      v3 = *(const floatx4*)(xp + 36);
    }

    // ---- Layer 1: [16x64] @ [64x128], W1 fragments streamed (L1-hot) ----
#pragma unroll
    for (int j = 0; j < 2; ++j) {
      int c8g = w + 4 * j;
      int c = c8g * 16 + cl;
      half8_t u0 = *(const half8_t*)(w1t + c * 64 + q * 8);
      half8_t u1 = *(const half8_t*)(w1t + c * 64 + 32 + q * 8);
      floatx4 acc = {0.f, 0.f, 0.f, 0.f};
      acc = __builtin_amdgcn_mfma_f32_16x16x32_f16(a0, u0, acc, 0, 0, 0);
      acc = __builtin_amdgcn_mfma_f32_16x16x32_f16(a1, u1, acc, 0, 0, 0);
#pragma unroll
      for (int i = 0; i < 4; ++i) {
        float v = acc[i] + bias1[j];
        v = v > 0.f ? v : 0.01f * v;  // LeakyReLU
        int row = q * 4 + i;
        int gs = ((c8g * 2 + (cl >> 3)) ^ row) & 15;  // XOR-swizzled group
        act1[row * 128 + gs * 8 + (cl & 7)] = (f16)v;
      }
    }
    __syncthreads();

    half8_t ha[4];
#pragma unroll
    for (int ks = 0; ks < 4; ++ks)
      ha[ks] = *(const half8_t*)(act1 + cl * 128 +
                                 ((((ks << 2) | q) ^ cl) << 3));

    // ---- Layer 2: [16x128] @ [128x128] (weights in VGPRs) ----
#pragma unroll
    for (int j = 0; j < 2; ++j) {
      int c8g = w + 4 * j;
      floatx4 acc = {0.f, 0.f, 0.f, 0.f};
#pragma unroll
      for (int ks = 0; ks < 4; ++ks)
        acc = __builtin_amdgcn_mfma_f32_16x16x32_f16(ha[ks], w2f[j][ks], acc,
                                                     0, 0, 0);
#pragma unroll
      for (int i = 0; i < 4; ++i) {
        float v = acc[i] + bias2[j];
        v = v > 0.f ? v : 0.01f * v;
        int row = q * 4 + i;
        int gs = ((c8g * 2 + (cl >> 3)) ^ row) & 15;
        act2[row * 128 + gs * 8 + (cl & 7)] = (f16)v;
      }
    }
    __syncthreads();

#pragma unroll
    for (int ks = 0; ks < 4; ++ks)
      ha[ks] = *(const half8_t*)(act2 + cl * 128 +
                                 ((((ks << 2) | q) ^ cl) << 3));

    // ---- Layer 3: [16x128] @ [128x136] + tanh -> expanded sym matrix ----
#pragma unroll
    for (int j = 0; j < 3; ++j) {
      int c8g = w + 4 * j;
      if (c8g < 9) {
        floatx4 acc = {0.f, 0.f, 0.f, 0.f};
#pragma unroll
        for (int ks = 0; ks < 4; ++ks)
          acc = __builtin_amdgcn_mfma_f32_16x16x32_f16(ha[ks], w3f[j][ks], acc,
                                                       0, 0, 0);
        int c = c8g * 16 + cl;
        if (c < 136) {
          int hi = hi_[j], lo = lo_[j];
#pragma unroll
          for (int i = 0; i < 4; ++i) {
            f16 v = (f16)fast_tanh(acc[i] + bias3[j]);
            int mb = (t * 16 + q * 4 + i) * 256;
            mats[mb + hi * 16 + lo] = v;
            mats[mb + lo * 16 + hi] = v;  // same addr when hi==lo (benign)
          }
        }
      }
    }
    // no barrier here: next tile touches act1 only after its own post-L1
    // barrier, and all act1/act2 reads for this tile already happened.
  }
  __syncthreads();  // all 32 symmetric matrices complete in LDS

  // ---- expm phase: 8 matrices per wave, one ds_read_b64 per matrix ----
  const int r = cl;
  floatx4 I4;
#pragma unroll
  for (int i = 0; i < 4; ++i) I4[i] = (r == q * 4 + i) ? 1.f : 0.f;

#pragma unroll 2
  for (int jj = 0; jj < 8; ++jj) {
    int m_loc = w * 8 + jj;
    const f16* md = mats + m_loc * 256;

    half4_t raw = *(const half4_t*)(md + r * 16 + q * 4);
    floatx4 b;
#pragma unroll
    for (int i = 0; i < 4; ++i) {
      float v = (float)raw[i];
      b[i] = (r == q * 4 + i) ? 4.f * v : 2.f * v;  // b = 2*Q, Q diag doubled
    }

    // expm #1: p = expm(2Q - m1 I);  Z/2 = e^{m1}/2 * p (exact algebra)
    float m1;
    floatx4 p = expm_c(b, I4, m1);
    float fac = __builtin_amdgcn_exp2f(m1 * 1.4426950408889634f - 1.0f);
    // expm #2: shift constant cancels in the final Frobenius normalization
    float m2;
    p = expm_c(p * fac, I4, m2);

    float n2 = wsum(dot4(p, p));
    float inv = __builtin_amdgcn_rsqf(n2);
    floatx4 o = p * inv;
    size_t mat = (size_t)(r0b + m_loc);
    // value_i = M[r][4q+i] -> out[mat*256 + r*16 + 4q + i]
    *(floatx4*)(out + mat * 256 + r * 16 + q * 4) = o;
  }
}

// ------------------------------------------------------------------
extern "C" void kernel_launch(void* const* d_in, const int* in_sizes, int n_in,
                              void* d_out, int out_size, void* d_ws,
                              size_t ws_size, hipStream_t stream) {
  const float* x = (const float*)d_in[0];
  const float* W1 = (const float*)d_in[1];
  const float* b1 = (const float*)d_in[2];
  const float* W2 = (const float*)d_in[3];
  const float* b2 = (const float*)d_in[4];
  const float* W3 = (const float*)d_in[5];
  const float* b3 = (const float*)d_in[6];
  float* out = (float*)d_out;
  f16* wt = (f16*)d_ws;

  prep_weights<<<168, 256, 0, stream>>>(W1, W2, W3, wt);
  fused_kernel<<<2048, 256, 0, stream>>>(x, b1, b2, b3, wt, out);
}

// Round 13
// 125.692 us; speedup vs baseline: 1.1025x; 1.1025x over previous
//
#include <hip/hip_runtime.h>
#include <math.h>

typedef _Float16 f16;
typedef _Float16 half4_t __attribute__((ext_vector_type(4)));
typedef _Float16 half8_t __attribute__((ext_vector_type(8)));
typedef float floatx4 __attribute__((ext_vector_type(4)));

// ------------------------------------------------------------------
// Kernel P: repack weights fp32 -> f16, transposed [col][k] so B-operand
// fragments (k-chunks of 8) are contiguous 16B loads.
// ------------------------------------------------------------------
__global__ __launch_bounds__(256) void prep_weights(
    const float* __restrict__ W1, const float* __restrict__ W2,
    const float* __restrict__ W3, f16* __restrict__ wt) {
  int t = blockIdx.x * 256 + threadIdx.x;
  if (t < 8192) {                       // W1t [128][64]
    int c = t >> 6, k = t & 63;
    wt[t] = (f16)W1[k * 128 + c];
  } else if (t < 24576) {               // W2t [128][128]
    int u = t - 8192;
    int c = u >> 7, k = u & 127;
    wt[t] = (f16)W2[k * 128 + c];
  } else if (t < 43008) {               // W3t [144][128], cols 136..143 zero
    int u = t - 24576;
    int c = u >> 7, k = u & 127;
    wt[t] = (f16)((c < 136) ? W3[k * 136 + c] : 0.0f);
  }
}

// fast tanh: tanh(x) = 1 - 2/(e^{2x}+1)
__device__ __forceinline__ float fast_tanh(float v) {
  float e = __builtin_amdgcn_exp2f(v * 2.885390081777926814f);  // 2*log2(e)
  return 1.0f - 2.0f * __builtin_amdgcn_rcpf(e + 1.0f);
}

// ---- DPP wave64 sum: row_shr 1/2/4/8 then row_bcast 15/31; total in lane 63.
template <int CTRL>
__device__ __forceinline__ float dpp_add(float v) {
  int t = __builtin_amdgcn_update_dpp(0, __builtin_bit_cast(int, v), CTRL,
                                      0xf, 0xf, true);
  return v + __builtin_bit_cast(float, t);
}
__device__ __forceinline__ float wsum(float v) {
  v = dpp_add<0x111>(v);  // row_shr:1
  v = dpp_add<0x112>(v);  // row_shr:2
  v = dpp_add<0x114>(v);  // row_shr:4
  v = dpp_add<0x118>(v);  // row_shr:8
  v = dpp_add<0x142>(v);  // row_bcast:15
  v = dpp_add<0x143>(v);  // row_bcast:31
  return __builtin_bit_cast(
      float, __builtin_amdgcn_readlane(__builtin_bit_cast(int, v), 63));
}

// round floatx4 -> half4 via packed RTZ converts
__device__ __forceinline__ half4_t to_h(floatx4 v) {
  auto p0 = __builtin_amdgcn_cvt_pkrtz(v[0], v[1]);
  auto p1 = __builtin_amdgcn_cvt_pkrtz(v[2], v[3]);
  half4_t h;
  h[0] = p0[0]; h[1] = p0[1]; h[2] = p1[0]; h[3] = p1[1];
  return h;
}

__device__ __forceinline__ float dot4(floatx4 a, floatx4 b) {
  return a[0] * b[0] + a[1] * b[1] + a[2] * b[2] + a[3] * b[3];
}

// ------------------------------------------------------------------
// p = expm(B - m I), m = trace/16. Canonical symmetric fragment layout:
// lane value_i = X[l&15][4*(l>>4)+i] is simultaneously a valid A, B and C/D
// layout for v_mfma_f32_16x16x16_f16 (polynomials of a symmetric matrix stay
// symmetric -> zero cross-lane data movement). Degree-4 Paterson-Stockmeyer,
// spectral bound theta <= 0.354 via Frobenius power-of-2 scaling.
// (Deg-8 tried in R11: +3.5 us -- this data's norms give s<=1 already, so
// the extra ~45 VALU/call bought nothing. Keep deg-4.)
// ------------------------------------------------------------------
__device__ __forceinline__ floatx4 expm_c(floatx4 b, floatx4 I4, float& m) {
  float s2 = wsum(dot4(b, b));
  float td = wsum(dot4(I4, b));
  m = td * 0.0625f;
  float fr2 = fmaxf(s2 - td * m, 1e-30f);  // ||B - mI||_F^2
  int e2 = (int)(__builtin_bit_cast(unsigned, fr2) >> 23) - 127;
  int s = (e2 + 5) >> 1;  // guarantees 2^-s * fr <= 2^-1.5 = 0.354
  s = s < 0 ? 0 : (s > 12 ? 12 : s);
  s = __builtin_amdgcn_readfirstlane(s);
  float sc = __builtin_bit_cast(float, (unsigned)(127 - s) << 23);  // 2^-s
  b = (b - I4 * m) * sc;
  half4_t bh = to_h(b);
  floatx4 zero = {0.f, 0.f, 0.f, 0.f};
  floatx4 a2 = __builtin_amdgcn_mfma_f32_16x16x16f16(bh, bh, zero, 0, 0, 0);
  // deg-4 Taylor: I + b + a2*(I/2 + b/6 + a2/24)
  floatx4 t = I4 * 0.5f + b * (1.f / 6.f) + a2 * (1.f / 24.f);
  floatx4 p = __builtin_amdgcn_mfma_f32_16x16x16f16(to_h(a2), to_h(t), I4 + b,
                                                    0, 0, 0);
  for (int k = 0; k < s; ++k) {
    half4_t ph = to_h(p);
    p = __builtin_amdgcn_mfma_f32_16x16x16f16(ph, ph, zero, 0, 0, 0);
  }
  return p;
}

// ------------------------------------------------------------------
// Fused kernel: the session's best measured configuration (R8, 50.3 us,
// total 126.7): stream W1 from global (L1-hot), W2/W3 register-resident,
// __launch_bounds__(256,3) = 168-reg cap (no spill, VGPR 84, occ 25.5%),
// 2048 blocks x 256 threads, ldata lives only in LDS (tril-packed [32][144]).
// Attempts that regressed and were reverted:
//   R9  stream W3 too, 4 blk/CU          -> 60 us (W3 on L3 critical path)
//   R10 8-wave blocks, 1 col-group/wave  -> 66 us (barrier overhead x2)
//   R11 deg-8 Paterson-Stockmeyer        -> 53.9 us (+5 us VALU, s<=1 anyway)
//   R12 expanded sym-matrix LDS layout   -> 61 us (write-side bank conflicts)
// Residual: ~26 us latency stall across wsum/MFMA chains at 41% VALU issue;
// structural repacks all cost more than they recover.
// ------------------------------------------------------------------
__global__ __launch_bounds__(256, 3) void fused_kernel(
    const float* __restrict__ x, const float* __restrict__ b1,
    const float* __restrict__ b2v, const float* __restrict__ b3,
    const f16* __restrict__ wt, float* __restrict__ out) {
  __shared__ f16 act1[2048];        // 16 rows x 128 cols (h1)
  __shared__ f16 act2[2048];        // 16 rows x 128 cols (h2)
  __shared__ f16 lds_ld[32 * 144];  // 32 rows x 144 chol cols (136 real)

  const int lane = threadIdx.x & 63;
  const int w = threadIdx.x >> 6;  // wave 0..3
  const int cl = lane & 15;        // A-row / C-col index
  const int q = lane >> 4;         // quad: k-chunk / C-row-group
  const f16* w1t = wt;             // [128][64]
  const f16* w2t = wt + 8192;      // [128][128]
  const f16* w3t = wt + 24576;     // [144][128]

  // ---- one-time: this wave's quarter of W2/W3 fragments + biases ----
  half8_t w2f[2][4], w3f[3][4];
  float bias1[2], bias2[2], bias3[3];
#pragma unroll
  for (int j = 0; j < 2; ++j) {
    int c8g = w + 4 * j;
    int c = c8g * 16 + cl;
#pragma unroll
    for (int ks = 0; ks < 4; ++ks)
      w2f[j][ks] = *(const half8_t*)(w2t + c * 128 + ks * 32 + q * 8);
    bias1[j] = b1[c];
    bias2[j] = b2v[c];
  }
#pragma unroll
  for (int j = 0; j < 3; ++j) {
    int c8g = w + 4 * j;
    int c8c = c8g < 9 ? c8g : 8;  // clamp so loads stay in-bounds (unused)
    int c = c8c * 16 + cl;
#pragma unroll
    for (int ks = 0; ks < 4; ++ks)
      w3f[j][ks] = *(const half8_t*)(w3t + c * 128 + ks * 32 + q * 8);
    int cc = c8g * 16 + cl;
    bias3[j] = (cc < 136) ? b3[cc] : 0.f;
  }

  const int r0b = blockIdx.x * 32;
  // prefetch row-tile 0's x rows (all 4 waves load same addrs: L1-hit)
  const float* xp = x + (size_t)(r0b + cl) * 64 + q * 8;
  floatx4 v0 = *(const floatx4*)xp;
  floatx4 v1 = *(const floatx4*)(xp + 4);
  floatx4 v2 = *(const floatx4*)(xp + 32);
  floatx4 v3 = *(const floatx4*)(xp + 36);

  for (int t = 0; t < 2; ++t) {
    half8_t a0, a1;
#pragma unroll
    for (int i = 0; i < 4; ++i) {
      a0[i] = (f16)v0[i]; a0[i + 4] = (f16)v1[i];
      a1[i] = (f16)v2[i]; a1[i + 4] = (f16)v3[i];
    }
    if (t == 0) {  // prefetch tile 1's x rows
      xp = x + (size_t)(r0b + 16 + cl) * 64 + q * 8;
      v0 = *(const floatx4*)xp;
      v1 = *(const floatx4*)(xp + 4);
      v2 = *(const floatx4*)(xp + 32);
      v3 = *(const floatx4*)(xp + 36);
    }

    // ---- Layer 1: [16x64] @ [64x128], W1 fragments streamed (L1-hot) ----
#pragma unroll
    for (int j = 0; j < 2; ++j) {
      int c8g = w + 4 * j;
      int c = c8g * 16 + cl;
      half8_t u0 = *(const half8_t*)(w1t + c * 64 + q * 8);
      half8_t u1 = *(const half8_t*)(w1t + c * 64 + 32 + q * 8);
      floatx4 acc = {0.f, 0.f, 0.f, 0.f};
      acc = __builtin_amdgcn_mfma_f32_16x16x32_f16(a0, u0, acc, 0, 0, 0);
      acc = __builtin_amdgcn_mfma_f32_16x16x32_f16(a1, u1, acc, 0, 0, 0);
#pragma unroll
      for (int i = 0; i < 4; ++i) {
        float v = acc[i] + bias1[j];
        v = v > 0.f ? v : 0.01f * v;  // LeakyReLU
        int row = q * 4 + i;
        int gs = ((c8g * 2 + (cl >> 3)) ^ row) & 15;  // XOR-swizzled group
        act1[row * 128 + gs * 8 + (cl & 7)] = (f16)v;
      }
    }
    __syncthreads();

    half8_t ha[4];
#pragma unroll
    for (int ks = 0; ks < 4; ++ks)
      ha[ks] = *(const half8_t*)(act1 + cl * 128 +
                                 ((((ks << 2) | q) ^ cl) << 3));

    // ---- Layer 2: [16x128] @ [128x128] (weights in VGPRs) ----
#pragma unroll
    for (int j = 0; j < 2; ++j) {
      int c8g = w + 4 * j;
      floatx4 acc = {0.f, 0.f, 0.f, 0.f};
#pragma unroll
      for (int ks = 0; ks < 4; ++ks)
        acc = __builtin_amdgcn_mfma_f32_16x16x32_f16(ha[ks], w2f[j][ks], acc,
                                                     0, 0, 0);
#pragma unroll
      for (int i = 0; i < 4; ++i) {
        float v = acc[i] + bias2[j];
        v = v > 0.f ? v : 0.01f * v;
        int row = q * 4 + i;
        int gs = ((c8g * 2 + (cl >> 3)) ^ row) & 15;
        act2[row * 128 + gs * 8 + (cl & 7)] = (f16)v;
      }
    }
    __syncthreads();

#pragma unroll
    for (int ks = 0; ks < 4; ++ks)
      ha[ks] = *(const half8_t*)(act2 + cl * 128 +
                                 ((((ks << 2) | q) ^ cl) << 3));

    // ---- Layer 3: [16x128] @ [128x136] + tanh -> ldata in LDS ----
#pragma unroll
    for (int j = 0; j < 3; ++j) {
      int c8g = w + 4 * j;
      if (c8g < 9) {
        floatx4 acc = {0.f, 0.f, 0.f, 0.f};
#pragma unroll
        for (int ks = 0; ks < 4; ++ks)
          acc = __builtin_amdgcn_mfma_f32_16x16x32_f16(ha[ks], w3f[j][ks], acc,
                                                       0, 0, 0);
        int c = c8g * 16 + cl;  // 0..143; cols >=136 are zero-weight scratch
#pragma unroll
        for (int i = 0; i < 4; ++i) {
          float v = fast_tanh(acc[i] + bias3[j]);
          lds_ld[(t * 16 + q * 4 + i) * 144 + c] = (f16)v;
        }
      }
    }
    // no barrier here: next tile touches act1 only after its own post-L1
    // barrier, and all act1/act2 reads for this tile already happened.
  }
  __syncthreads();  // ldata complete in LDS

  // ---- expm phase: 8 matrices per wave, ldata read from LDS ----
  const int r = cl;
#pragma unroll 2
  for (int jj = 0; jj < 8; ++jj) {
    int m_loc = w * 8 + jj;
    const f16* ld = lds_ld + m_loc * 144;

    floatx4 b, I4;
#pragma unroll
    for (int i = 0; i < 4; ++i) {
      int k = q * 4 + i;
      int hi = r > k ? r : k;
      int lo = r + k - hi;
      float v = (float)ld[hi * (hi + 1) / 2 + lo];  // tril row-major index
      bool d = (r == k);
      I4[i] = d ? 1.f : 0.f;
      b[i] = d ? 4.f * v : 2.f * v;  // b = 2*Q (Q diag = 2*ldata)
    }

    // expm #1: p = expm(2Q - m1 I);  Z/2 = e^{m1}/2 * p (exact algebra)
    float m1;
    floatx4 p = expm_c(b, I4, m1);
    float fac = __builtin_amdgcn_exp2f(m1 * 1.4426950408889634f - 1.0f);
    // expm #2: shift constant cancels in the final Frobenius normalization
    float m2;
    p = expm_c(p * fac, I4, m2);

    float n2 = wsum(dot4(p, p));
    float inv = __builtin_amdgcn_rsqf(n2);
    floatx4 o = p * inv;
    size_t mat = (size_t)(r0b + m_loc);
    // value_i = M[r][4q+i] -> out[mat*256 + r*16 + 4q + i]
    *(floatx4*)(out + mat * 256 + r * 16 + q * 4) = o;
  }
}

// ------------------------------------------------------------------
extern "C" void kernel_launch(void* const* d_in, const int* in_sizes, int n_in,
                              void* d_out, int out_size, void* d_ws,
                              size_t ws_size, hipStream_t stream) {
  const float* x = (const float*)d_in[0];
  const float* W1 = (const float*)d_in[1];
  const float* b1 = (const float*)d_in[2];
  const float* W2 = (const float*)d_in[3];
  const float* b2 = (const float*)d_in[4];
  const float* W3 = (const float*)d_in[5];
  const float* b3 = (const float*)d_in[6];
  float* out = (float*)d_out;
  f16* wt = (f16*)d_ws;

  prep_weights<<<168, 256, 0, stream>>>(W1, W2, W3, wt);
  fused_kernel<<<2048, 256, 0, stream>>>(x, b1, b2, b3, wt, out);
}